// Round 14
// baseline (309.724 us; speedup 1.0000x reference)
//
#include <hip/hip_runtime.h>

// Problem constants
#define NN 100000      // nodes
#define NE 600000      // edges
#define D  128         // feature dim in (both layers)
#define DOUT2 96
#define NREL 4
#define KREL 512       // NREL * D
#define KCAT 640       // KREL + D
#define SCAN_B 98      // ceil(NN / 1024)
#define EMAX 1024      // staged edge-index capacity per block (mean 192)

typedef short short8 __attribute__((ext_vector_type(8)));   // 8 bf16
typedef float f32x4  __attribute__((ext_vector_type(4)));

// fp32 -> bf16 round-to-nearest-even (finite inputs)
__device__ __forceinline__ ushort f2bf(float x) {
    unsigned u = __builtin_bit_cast(unsigned, x);
    u += 0x7fffu + ((u >> 16) & 1u);
    return (ushort)(u >> 16);
}
__device__ __forceinline__ float bfhi(unsigned u) {
    return __builtin_bit_cast(float, u & 0xffff0000u);
}
__device__ __forceinline__ float bflo(unsigned u) {
    return __builtin_bit_cast(float, u << 16);
}

// ---------------------------------------------------------------------------
// Fused independent prep: zero cnt, zero fill, x->bf16, pack Wcp1, pack Wcp2.
__global__ void prep0(const float* __restrict__ x, ushort* __restrict__ Xb,
                      const float* __restrict__ W1, const float* __restrict__ root1,
                      short* __restrict__ Wp1,
                      const float* __restrict__ W2, const float* __restrict__ root2,
                      short* __restrict__ Wp2,
                      float* __restrict__ cnt, int* __restrict__ fill) {
    int i = blockIdx.x * 256 + threadIdx.x;
    const int S0 = (NN * NREL) / 4;   // 100000 float4 zeros of cnt
    const int S1 = NN / 4;            // 25000 int4 zeros of fill
    const int S2 = (NN * D) / 4;      // 3200000 float4->ushort4 converts
    const int S3 = KCAT * D;          // 81920 pack1 elements
    const int S4 = KCAT * DOUT2;      // 61440 pack2 elements
    if (i < S0) { ((float4*)cnt)[i] = make_float4(0.f, 0.f, 0.f, 0.f); return; }
    i -= S0;
    if (i < S1) { ((int4*)fill)[i] = make_int4(0, 0, 0, 0); return; }
    i -= S1;
    if (i < S2) {
        float4 v = ((const float4*)x)[i];
        ushort4 o;
        o.x = f2bf(v.x); o.y = f2bf(v.y); o.z = f2bf(v.z); o.w = f2bf(v.w);
        ((ushort4*)Xb)[i] = o;
        return;
    }
    i -= S2;
    if (i < S3) {   // Wcp[kq][n][j] = Wcat[kq*8+j][n], BN = 128
        int j = i & 7, rest = i >> 3;
        int n = rest % D, kq = rest / D;
        int k = kq * 8 + j;
        float v = (k < KREL) ? W1[(size_t)k * D + n] : root1[(size_t)(k - KREL) * D + n];
        Wp1[i] = (short)f2bf(v);
        return;
    }
    i -= S3;
    if (i < S4) {   // BN = 96
        int j = i & 7, rest = i >> 3;
        int n = rest % DOUT2, kq = rest / DOUT2;
        int k = kq * 8 + j;
        float v = (k < KREL) ? W2[(size_t)k * DOUT2 + n] : root2[(size_t)(k - KREL) * DOUT2 + n];
        Wp2[i] = (short)f2bf(v);
        return;
    }
}

// ---------------------------------------------------------------------------
// cnt[v][r] = #edges with dst=v, etype=r
__global__ void count_deg(const int* __restrict__ dst,
                          const int* __restrict__ et,
                          float* __restrict__ cnt) {
    int e = blockIdx.x * blockDim.x + threadIdx.x;
    if (e < NE) unsafeAtomicAdd(&cnt[dst[e] * NREL + et[e]], 1.0f);
}

// ---------------------------------------------------------------------------
// Prefix sum of per-node degree -> off[0..NN] (3-kernel scan)
__global__ void scan1(const float* __restrict__ cnt, int* __restrict__ bsum) {
    __shared__ int s[256];
    int tid = threadIdx.x;
    int base = blockIdx.x * 1024 + tid * 4;
    int t = 0;
    for (int i = 0; i < 4; i++) {
        int v = base + i;
        if (v < NN) {
            float4 c = *(const float4*)&cnt[(size_t)v * 4];
            t += (int)(c.x + c.y + c.z + c.w);
        }
    }
    s[tid] = t; __syncthreads();
    for (int o = 128; o > 0; o >>= 1) {
        if (tid < o) s[tid] += s[tid + o];
        __syncthreads();
    }
    if (tid == 0) bsum[blockIdx.x] = s[0];
}

__global__ void scan2(int* __restrict__ bsum) {  // 1 block of 128; exclusive in-place
    __shared__ int s[128];
    int tid = threadIdx.x;
    int mine = (tid < SCAN_B) ? bsum[tid] : 0;
    s[tid] = mine; __syncthreads();
    for (int o = 1; o < 128; o <<= 1) {
        int v = (tid >= o) ? s[tid - o] : 0;
        __syncthreads();
        s[tid] += v;
        __syncthreads();
    }
    if (tid < SCAN_B) bsum[tid] = s[tid] - mine;
}

__global__ void scan3(const float* __restrict__ cnt, const int* __restrict__ bsum,
                      int* __restrict__ off) {
    __shared__ int s[256];
    int tid = threadIdx.x;
    int base = blockIdx.x * 1024 + tid * 4;
    int d[4]; int t = 0;
    for (int i = 0; i < 4; i++) {
        int v = base + i; d[i] = 0;
        if (v < NN) {
            float4 c = *(const float4*)&cnt[(size_t)v * 4];
            d[i] = (int)(c.x + c.y + c.z + c.w);
        }
        t += d[i];
    }
    int mine = t;
    s[tid] = t; __syncthreads();
    for (int o = 1; o < 256; o <<= 1) {
        int v = (tid >= o) ? s[tid - o] : 0;
        __syncthreads();
        s[tid] += v;
        __syncthreads();
    }
    int ex = s[tid] - mine + bsum[blockIdx.x];
    for (int i = 0; i < 4; i++) {
        int v = base + i;
        if (v < NN) { off[v] = ex; ex += d[i]; }
    }
    if (blockIdx.x == 0 && tid == 0) off[NN] = NE;
}

// ---------------------------------------------------------------------------
// Bucket edges by dst; packed (src<<2)|etype
__global__ void bucket_edges(const int* __restrict__ src, const int* __restrict__ dst,
                             const int* __restrict__ et, const int* __restrict__ off,
                             int* __restrict__ fill, int* __restrict__ srcpk) {
    int e = blockIdx.x * blockDim.x + threadIdx.x;
    if (e >= NE) return;
    int dn = dst[e];
    int pos = off[dn] + atomicAdd(&fill[dn], 1);
    srcpk[pos] = (src[e] << 2) | et[e];
}

// ---------------------------------------------------------------------------
// Fused RGCN layer — R13 frame + clamped 8-slot head batch (R14).
// Block = 256 threads (4 waves), 32 dst nodes; LDS: 32 KB A-tile + 4 KB idx
// + off/cnt stage (~37.9 KB, 4 blocks/CU).
// CAUSAL MODEL (R12 +7%, R13 +3.5%): bound by serial gather round trips
// per chain. R14 halves them: a clamped 8-slot HEAD issues min(deg,8)
// gathers in ONE trip (P(deg<=8)~0.85 -> E[trips/node] 1.9 -> ~1.2).
// Unused slots re-read slot 0's edge and are zero-gated (t_=4). Wasted
// gathers (~2/node at deg<8) hit L2/L3 only — R10 proved latency >>
// throughput here.
// Register budget: indices come from LDS (no global idx loads in flight,
// unlike R8's spill); __launch_bounds__(256,3) raises the VGPR ceiling to
// ~170. This is occupancy-FREE: LDS caps residency at 4 blocks/CU = 16
// waves, which only requires VGPR <= 128 (64/128/256 steps) — the
// allocator can take ~80-112 VGPR without losing a wave.
// Spill tripwire: WRITE_SIZE must stay == output (25000 KiB L1).
//   XOR-swizzled staging (0 conflicts), root-MFMA hoist, phase-2 quadrant
//   split: identical to R13 (72.8 us measured).
template <int BN, bool RELU, bool OUT_BF16>
__global__ __launch_bounds__(256, 3) void rgcn_fused(
    const ushort* __restrict__ Xb,   // [M,128] bf16
    const int*   __restrict__ srcpk, // [NE] bucketed, (src<<2)|t
    const int*   __restrict__ off,   // [M+1]
    const float* __restrict__ cnt,   // [M,4]
    const short* __restrict__ Wcp,   // [80][BN][8] bf16
    const float* __restrict__ bias,  // [BN]
    void*        __restrict__ Cout,  // [M,BN] bf16 or f32
    int M) {
    constexpr int NFW = (BN / 16 + 1) / 2;   // frags per wave: 4 (BN=128) / 3 (BN=96)
    __shared__ short At[64 * 32 * 8];        // 32 KB
    __shared__ int   eidx[EMAX];             // 4 KB staged (src<<2)|t
    __shared__ int   soff[33];               // staged off[v0..v0+32]
    __shared__ float scnt[32 * 4];           // staged cnt rows

    const int tid  = threadIdx.x;
    const int wave = tid >> 6;
    const int lane = tid & 63;
    const int l    = lane & 15;     // phase1: feat group / phase2: m16
    const int qw   = lane >> 4;     // phase1: quarter / phase2: k-quad q
    const int g    = wave * 4 + qw; // chain id 0..15
    const int v0   = blockIdx.x * 32;

    // ---- cooperative prologue: stage off, cnt, and edge indices ----
    const int ebase = off[v0];
    const int nE    = off[v0 + 32] - ebase;
    const bool useL = (nE <= EMAX);
    if (tid < 33) soff[tid] = off[v0 + tid];
    if (tid >= 64 && tid < 96) {  // different wave than soff loaders: overlap
        int t2 = tid - 64;
        *(float4*)&scnt[t2 * 4] = *(const float4*)&cnt[(size_t)(v0 + t2) * 4];
    }
    if (useL) {
        for (int i = tid; i < nE; i += 256) eidx[i] = srcpk[ebase + i];
    }
    __syncthreads();

    // ---- phase 1: aggregate 32 nodes (2 per chain) ----
    // EDGE_ACC_G: gate==0 forces t_=4 -> all selects false -> zero contribution
#define EDGE_ACC_G(PK, XB, GOK) {                                           \
        int t_ = (GOK) ? ((PK) & 3) : 4;                                    \
        float s0 = (t_ == 0) ? nrm0 : 0.0f;                                 \
        float s1 = (t_ == 1) ? nrm1 : 0.0f;                                 \
        float s2 = (t_ == 2) ? nrm2 : 0.0f;                                 \
        float s3 = (t_ == 3) ? nrm3 : 0.0f;                                 \
        float xf[8];                                                        \
        xf[0] = bflo(XB.x); xf[1] = bfhi(XB.x);                             \
        xf[2] = bflo(XB.y); xf[3] = bfhi(XB.y);                             \
        xf[4] = bflo(XB.z); xf[5] = bfhi(XB.z);                             \
        xf[6] = bflo(XB.w); xf[7] = bfhi(XB.w);                             \
        _Pragma("unroll")                                                   \
        for (int j = 0; j < 8; j++) {                                       \
            acc[0][j] += s0 * xf[j];                                        \
            acc[1][j] += s1 * xf[j];                                        \
            acc[2][j] += s2 * xf[j];                                        \
            acc[3][j] += s3 * xf[j];                                        \
        } }
#define EDGE_ACC(PK, XB) EDGE_ACC_G(PK, XB, 1)

#define PHASE1_BODY(LOADI)                                                  \
    _Pragma("unroll")                                                       \
    for (int half = 0; half < 2; half++) {                                  \
        int nv = g + half * 16;                                             \
        float acc[4][8];                                                    \
        _Pragma("unroll")                                                   \
        for (int r = 0; r < 4; r++)                                         \
            _Pragma("unroll")                                               \
            for (int j = 0; j < 8; j++) acc[r][j] = 0.0f;                   \
        float4 c4 = *(const float4*)&scnt[nv * 4];                          \
        float nrm0 = 1.0f / fmaxf(c4.x, 1.0f);                              \
        float nrm1 = 1.0f / fmaxf(c4.y, 1.0f);                              \
        float nrm2 = 1.0f / fmaxf(c4.z, 1.0f);                              \
        float nrm3 = 1.0f / fmaxf(c4.w, 1.0f);                              \
        int e = soff[nv], end = soff[nv + 1];                               \
        int rem = end - e;                                                  \
        if (rem > 0) {   /* clamped 8-slot head: ONE trip for min(rem,8) */ \
            int c1 = rem > 1, c2 = rem > 2, c3 = rem > 3;                   \
            int c4g = rem > 4, c5 = rem > 5, c6 = rem > 6, c7 = rem > 7;    \
            int p0 = LOADI(e);                                              \
            int p1 = LOADI(e + (c1  ? 1 : 0));                              \
            int p2 = LOADI(e + (c2  ? 2 : 0));                              \
            int p3 = LOADI(e + (c3  ? 3 : 0));                              \
            int p4 = LOADI(e + (c4g ? 4 : 0));                              \
            int p5 = LOADI(e + (c5  ? 5 : 0));                              \
            int p6 = LOADI(e + (c6  ? 6 : 0));                              \
            int p7 = LOADI(e + (c7  ? 7 : 0));                              \
            uint4 x0 = *(const uint4*)&Xb[(size_t)(p0 >> 2) * D + l * 8];   \
            uint4 x1 = *(const uint4*)&Xb[(size_t)(p1 >> 2) * D + l * 8];   \
            uint4 x2 = *(const uint4*)&Xb[(size_t)(p2 >> 2) * D + l * 8];   \
            uint4 x3 = *(const uint4*)&Xb[(size_t)(p3 >> 2) * D + l * 8];   \
            uint4 x4 = *(const uint4*)&Xb[(size_t)(p4 >> 2) * D + l * 8];   \
            uint4 x5 = *(const uint4*)&Xb[(size_t)(p5 >> 2) * D + l * 8];   \
            uint4 x6 = *(const uint4*)&Xb[(size_t)(p6 >> 2) * D + l * 8];   \
            uint4 x7 = *(const uint4*)&Xb[(size_t)(p7 >> 2) * D + l * 8];   \
            EDGE_ACC(p0, x0);                                               \
            EDGE_ACC_G(p1, x1, c1);  EDGE_ACC_G(p2, x2, c2);                \
            EDGE_ACC_G(p3, x3, c3);  EDGE_ACC_G(p4, x4, c4g);               \
            EDGE_ACC_G(p5, x5, c5);  EDGE_ACC_G(p6, x6, c6);                \
            EDGE_ACC_G(p7, x7, c7);                                         \
            e += (rem < 8) ? rem : 8;                                       \
        }                                                                   \
        for (; e + 3 < end; e += 4) {   /* 4-wide loop for deg > 8 */       \
            int p0 = LOADI(e),     p1 = LOADI(e + 1);                       \
            int p2 = LOADI(e + 2), p3 = LOADI(e + 3);                       \
            uint4 x0 = *(const uint4*)&Xb[(size_t)(p0 >> 2) * D + l * 8];   \
            uint4 x1 = *(const uint4*)&Xb[(size_t)(p1 >> 2) * D + l * 8];   \
            uint4 x2 = *(const uint4*)&Xb[(size_t)(p2 >> 2) * D + l * 8];   \
            uint4 x3 = *(const uint4*)&Xb[(size_t)(p3 >> 2) * D + l * 8];   \
            EDGE_ACC(p0, x0); EDGE_ACC(p1, x1);                             \
            EDGE_ACC(p2, x2); EDGE_ACC(p3, x3);                             \
        }                                                                   \
        if (e < end) {   /* clamped tail: 1..3 edges, ONE gather trip */    \
            int rm2 = end - e;                                              \
            int ea = e + ((rm2 > 1) ? 1 : 0);                               \
            int eb = e + ((rm2 > 2) ? 2 : 0);                               \
            int p0 = LOADI(e), p1 = LOADI(ea), p2 = LOADI(eb);              \
            uint4 x0 = *(const uint4*)&Xb[(size_t)(p0 >> 2) * D + l * 8];   \
            uint4 x1 = *(const uint4*)&Xb[(size_t)(p1 >> 2) * D + l * 8];   \
            uint4 x2 = *(const uint4*)&Xb[(size_t)(p2 >> 2) * D + l * 8];   \
            EDGE_ACC(p0, x0);                                               \
            EDGE_ACC_G(p1, x1, rm2 > 1);                                    \
            EDGE_ACC_G(p2, x2, rm2 > 2);                                    \
        }                                                                   \
        _Pragma("unroll")                                                   \
        for (int r = 0; r < 4; r++) {                                       \
            short8 w;                                                       \
            _Pragma("unroll")                                               \
            for (int j = 0; j < 8; j++) w[j] = (short)f2bf(acc[r][j]);      \
            int kq = r * 16 + l;                                            \
            *(short8*)&At[(kq * 32 + (nv ^ (kq & 7))) * 8] = w;             \
        }                                                                   \
    }

#define LOADI_LDS(E)  eidx[(E) - ebase]
#define LOADI_GLB(E)  srcpk[(E)]
    if (useL) { PHASE1_BODY(LOADI_LDS) }
    else      { PHASE1_BODY(LOADI_GLB) }
#undef LOADI_LDS
#undef LOADI_GLB
#undef PHASE1_BODY
#undef EDGE_ACC
#undef EDGE_ACC_G

    // ---- phase 2 setup ----
    const int m16   = l;
    const int q     = qw;
    const int mt    = wave & 1;           // m-half (16 nodes)
    const int nbase = (wave >> 1) * NFW * 16;   // n-offset
    f32x4 acc2[NFW];
#pragma unroll
    for (int i = 0; i < NFW; i++) acc2[i] = (f32x4)0.0f;

    // root part first (k = 512..639, global-only operands): phase-1 registers
    // are dead here; fast waves do these MFMAs while slow chains gather.
    {
        int rowc = v0 + mt * 16 + m16;
        const ushort* Xrow = Xb + (size_t)rowc * D;
#pragma unroll
        for (int s2 = 0; s2 < 4; s2++) {
            short8 af = *(const short8*)&Xrow[s2 * 32 + q * 8];
            const short* bbase = Wcp + ((size_t)((16 + s2) * 4 + q) * BN + nbase + m16) * 8;
#pragma unroll
            for (int nf = 0; nf < NFW; nf++) {
                short8 bf = *(const short8*)(bbase + nf * 128);
                acc2[nf] = __builtin_amdgcn_mfma_f32_16x16x32_bf16(af, bf, acc2[nf], 0, 0, 0);
            }
        }
    }

    __syncthreads();

    // ---- phase 2: 32x512 @ 512xBN from LDS, one quadrant per wave ----
#pragma unroll 4
    for (int ks = 0; ks < 16; ks++) {
        int kq = ks * 4 + q;
        short8 af = *(const short8*)&At[(kq * 32 + ((mt * 16 + m16) ^ (kq & 7))) * 8];
        const short* bbase = Wcp + ((size_t)kq * BN + nbase + m16) * 8;
#pragma unroll
        for (int nf = 0; nf < NFW; nf++) {
            short8 bf = *(const short8*)(bbase + nf * 128);
            acc2[nf] = __builtin_amdgcn_mfma_f32_16x16x32_bf16(af, bf, acc2[nf], 0, 0, 0);
        }
    }

    // ---- epilogue ----
#pragma unroll
    for (int nf = 0; nf < NFW; nf++) {
        int n = nbase + nf * 16 + m16;
        float b = bias[n];
#pragma unroll
        for (int r = 0; r < 4; r++) {
            int m = v0 + mt * 16 + q * 4 + r;
            float vv = acc2[nf][r] + b;
            if (RELU) vv = fmaxf(vv, 0.0f);
            if (OUT_BF16) ((ushort*)Cout)[(size_t)m * BN + n] = f2bf(vv);
            else          ((float*)Cout)[(size_t)m * BN + n]  = vv;
        }
    }
}

// ---------------------------------------------------------------------------
extern "C" void kernel_launch(void* const* d_in, const int* in_sizes, int n_in,
                              void* d_out, int out_size, void* d_ws, size_t ws_size,
                              hipStream_t stream) {
    const float* x     = (const float*)d_in[0];
    const int*   ei    = (const int*)d_in[1];
    const int*   et    = (const int*)d_in[2];
    const float* W1    = (const float*)d_in[3];
    const float* root1 = (const float*)d_in[4];
    const float* b1    = (const float*)d_in[5];
    const float* W2    = (const float*)d_in[6];
    const float* root2 = (const float*)d_in[7];
    const float* b2    = (const float*)d_in[8];
    const int* srcp = ei;
    const int* dstp = ei + NE;
    float* out = (float*)d_out;

    // Workspace layout (all segments 16-B aligned)
    short*  Wp1  = (short*)d_ws;                          // 640*128 bf16
    short*  Wp2  = Wp1 + (size_t)KCAT * D;                // 640*96  bf16
    ushort* Xb   = (ushort*)(Wp2 + (size_t)KCAT * DOUT2); // NN*128 bf16
    ushort* h    = Xb + (size_t)NN * D;                   // NN*128 bf16
    float*  cnt  = (float*)(h + (size_t)NN * D);          // NN*4 f32
    int*    off  = (int*)(cnt + (size_t)NN * NREL);       // NN+1
    int*    fill = off + (NN + 1);                        // NN
    int*    bsum = fill + NN;                             // 128
    int*    srcpk= bsum + 128;                            // NE

    // ---- prep (shared by both layers) ----
    {
        const int S = (NN * NREL) / 4 + NN / 4 + (NN * D) / 4 + KCAT * D + KCAT * DOUT2;
        prep0<<<(S + 255) / 256, 256, 0, stream>>>(x, Xb, W1, root1, Wp1,
                                                   W2, root2, Wp2, cnt, fill);
    }
    count_deg<<<(NE + 255) / 256, 256, 0, stream>>>(dstp, et, cnt);
    scan1<<<SCAN_B, 256, 0, stream>>>(cnt, bsum);
    scan2<<<1, 128, 0, stream>>>(bsum);
    scan3<<<SCAN_B, 256, 0, stream>>>(cnt, bsum, off);
    bucket_edges<<<(NE + 255) / 256, 256, 0, stream>>>(srcp, dstp, et, off, fill, srcpk);

    const int fblocks = NN / 32;  // 3125 (exact)

    // ---- Layer 1: h = relu(agg(x) @ W1cat + b1), bf16 out ----
    rgcn_fused<128, true, true><<<fblocks, 256, 0, stream>>>(
        Xb, srcpk, off, cnt, Wp1, b1, h, NN);
    // ---- Layer 2: out = agg(h) @ W2cat + b2, f32 out ----
    rgcn_fused<96, false, false><<<fblocks, 256, 0, stream>>>(
        h, srcpk, off, cnt, Wp2, b2, out, NN);
}